// Round 7
// baseline (243.859 us; speedup 1.0000x reference)
//
#include <hip/hip_runtime.h>
#include <cstdint>

typedef __attribute__((ext_vector_type(4))) int int32x4;
typedef __attribute__((ext_vector_type(16))) int int32x16;

#define GLOBAL_AS __attribute__((address_space(1)))
#define LDS_AS    __attribute__((address_space(3)))

// ---------------------------------------------------------------------------
// Kernel 0: pack int32-carried weight [N*K] (values in [-128,127]) to int8.
// ---------------------------------------------------------------------------
__global__ __launch_bounds__(256) void pack_w(
    const int* __restrict__ w32, uint32_t* __restrict__ w8_as_u32)
{
    const size_t i = (size_t)blockIdx.x * 256 + threadIdx.x; // 4 elems each
    const int4 v = ((const int4*)w32)[i];
    w8_as_u32[i] = (v.x & 0xff) | ((v.y & 0xff) << 8) |
                   ((v.z & 0xff) << 16) | ((uint32_t)(v.w & 0xff) << 24);
}

// ---------------------------------------------------------------------------
// Kernel 1: per-row dynamic symmetric int8 quantization (K=4096).
// ---------------------------------------------------------------------------
__global__ __launch_bounds__(256) void quant_rows(
    const float* __restrict__ in, int8_t* __restrict__ q,
    float* __restrict__ sa, int K)
{
    const int row = blockIdx.x;
    const float4* rp = (const float4*)(in + (size_t)row * K);
    const int t = threadIdx.x;

    float amax = 0.f;
    float4 v[4];
#pragma unroll
    for (int i = 0; i < 4; ++i) {
        v[i] = rp[t + (i << 8)];
        amax = fmaxf(amax,
               fmaxf(fmaxf(fabsf(v[i].x), fabsf(v[i].y)),
                     fmaxf(fabsf(v[i].z), fabsf(v[i].w))));
    }

#pragma unroll
    for (int off = 32; off; off >>= 1)
        amax = fmaxf(amax, __shfl_xor(amax, off));
    __shared__ float smax[4];
    if ((t & 63) == 0) smax[t >> 6] = amax;
    __syncthreads();
    amax = fmaxf(fmaxf(smax[0], smax[1]), fmaxf(smax[2], smax[3]));

    const float scale = (amax > 0.f) ? (amax / 127.f) : 1.f;
    if (t == 0) sa[row] = scale;
    const float rs = 1.f / scale;

    int* qrow = (int*)(q + (size_t)row * K);
#pragma unroll
    for (int i = 0; i < 4; ++i) {
        int a = __float2int_rn(v[i].x * rs);
        int b = __float2int_rn(v[i].y * rs);
        int c = __float2int_rn(v[i].z * rs);
        int d = __float2int_rn(v[i].w * rs);
        a = max(-128, min(127, a));
        b = max(-128, min(127, b));
        c = max(-128, min(127, c));
        d = max(-128, min(127, d));
        qrow[t + (i << 8)] = (a & 0xff) | ((b & 0xff) << 8) |
                             ((c & 0xff) << 16) | ((d & 0xff) << 24);
    }
}

// ---------------------------------------------------------------------------
// Kernel 2 (R7): int8 GEMM, 256x256 tile, 4 waves x (128x128), 32x32x32 MFMA.
//
// FRAGMENT-MAJOR LDS: each (32-row-block, kk) operand fragment is stored as
// one contiguous 1 KiB block:  off = mblk*2048 + kk*1024 + h*512 + l31*16.
// Every ds_read_b128 is then base + lane*16 (contiguous 1 KiB per wave) —
// the pattern measured 0-conflict in R3; split-span reads cost exactly
// 4 cyc/read (R4/R5/R6, swizzle-independent). Achieved by permuting the
// GLOBAL source of global_load_lds (LDS dest linear, rule #21):
//   slot j (0..511 per 8 KiB chunk):  row = (j>>7)*32 + (j&31),
//                                     col16 = ((j>>6)&1)*2 + ((j>>5)&1).
// Thread t writes slots t and t+256 (same col, row+64).
//
// GROUPED K: 2 K-tiles (BK=128) per barrier. Ring-2 of 64 KiB groups
// (total 128 KiB). Group body: stage group g+1 into ring (g+1)&1 (opposite
// half -> WAR-safe), compute kt=0,1 (16 ds_read + 32 MFMA each), vmcnt(0)
// (stage issued early -> wait absorbed by ~2400 cyc compute), one barrier.
//
// Group region layout (64 KiB): A[kt][mblk][kk][h][l31] at kt*16384 +
// mblk*2048 + kk*1024 + lane*16;  B same at +32768.
//
// Fragment maps (32x32 i8): A row = lane&31, k = (lane>>5)*16 + byte;
// B col = lane&31, same k. C/D: col = lane&31,
// row = (reg&3) + 8*(reg>>2) + 4*(lane>>5)  [guide-verified, dtype-indep].
// ---------------------------------------------------------------------------
__device__ __forceinline__ void async_load16(const int8_t* g, int8_t* lds) {
    __builtin_amdgcn_global_load_lds((const GLOBAL_AS char*)g,
                                     (LDS_AS char*)lds, 16, 0, 0);
}

__global__ __launch_bounds__(256, 1) void w8a8_gemm(
    const int8_t* __restrict__ Aq, const int8_t* __restrict__ W,
    const float* __restrict__ sa, const float* __restrict__ wsc,
    const float* __restrict__ bias, float* __restrict__ out,
    int M, int N, int K)
{
    __shared__ int8_t lds[2 * 65536]; // 128 KiB -> 1 block/CU

    const int NB = N >> 8; // N/256
    const int nwg = gridDim.x;
    // XCD-aware swizzle (nwg % 8 == 0 -> bijective)
    const int cpx = nwg >> 3;
    const int wg = (blockIdx.x & 7) * cpx + (blockIdx.x >> 3);
    const int bm = wg / NB, bn = wg % NB;

    const int t = threadIdx.x;          // 0..255, 4 waves
    const int lane = t & 63, wid = t >> 6;
    const int wr = wid >> 1, wc = wid & 1;   // 2x2 wave grid, 128x128 each
    const int l31 = lane & 31, h = lane >> 5;

    // ---- staging: fragment-major inverse map for slots t and t+256 ----
    const int srow = ((t >> 7) << 5) + (t & 31);              // 0..63
    const int scol = ((((t >> 6) & 1) * 2 + ((t >> 5) & 1)) << 4);
    const int8_t* gA = Aq + ((size_t)bm * 256 + srow) * (size_t)K + scol;
    const int8_t* gB = W  + ((size_t)bn * 256 + srow) * (size_t)K + scol;
    const size_t rstep = (size_t)64 * K;   // slot t+256: +64 rows
    const size_t hstep = (size_t)128 * K;  // A/B second chunk: +128 rows
    int8_t* ldsw = &lds[t * 16];

    // stage one 2-K-tile group into ring slot `slot`; kbyte = group*128
    auto stage_group = [&](int slot, int kbyte) {
#pragma unroll
        for (int c = 0; c < 8; ++c) {
            const int sub = c & 3;      // 0,1: A halves; 2,3: B halves
            const int kt = c >> 2;
            const int8_t* s0 = (sub < 2 ? gA : gB) +
                               (size_t)(sub & 1) * hstep + kbyte + kt * 64;
            int8_t* d0 = ldsw + slot * 65536 + (sub >= 2 ? 32768 : 0) +
                         kt * 16384 + (sub & 1) * 8192;
            async_load16(s0, d0);
            async_load16(s0 + rstep, d0 + 4096);
        }
    };

    // ---- fragment read bases (contiguous: base + lane*16) ----
    const int aoff = wr * 8192 + lane * 16;          // + m*2048 + kk*1024
    const int boff = 32768 + wc * 8192 + lane * 16;  // + n*2048 + kk*1024

    int32x16 acc[4][4];
#pragma unroll
    for (int m = 0; m < 4; ++m)
#pragma unroll
        for (int n = 0; n < 4; ++n)
#pragma unroll
            for (int rgi = 0; rgi < 16; ++rgi)
                acc[m][n][rgi] = 0;

    const int NG = K >> 7; // 32 groups of 2 K-tiles

    // prologue: stage group 0 into ring 0
    stage_group(0, 0);
    asm volatile("s_waitcnt vmcnt(0)" ::: "memory");
    asm volatile("s_barrier" ::: "memory");

    for (int g = 0; g < NG; ++g) {
        const int rbase = (g & 1) * 65536;

        if (g + 1 < NG) stage_group((g + 1) & 1, (g + 1) << 7);

#pragma unroll
        for (int kt = 0; kt < 2; ++kt) {
            const int tb = rbase + kt * 16384;
            int32x4 a0[4], b0[4], a1[4], b1[4];
#pragma unroll
            for (int m = 0; m < 4; ++m) {
                a0[m] = *(const int32x4*)&lds[tb + aoff + m * 2048];
                a1[m] = *(const int32x4*)&lds[tb + aoff + m * 2048 + 1024];
            }
#pragma unroll
            for (int n = 0; n < 4; ++n) {
                b0[n] = *(const int32x4*)&lds[tb + boff + n * 2048];
                b1[n] = *(const int32x4*)&lds[tb + boff + n * 2048 + 1024];
            }
#pragma unroll
            for (int m = 0; m < 4; ++m)
#pragma unroll
                for (int n = 0; n < 4; ++n)
                    acc[m][n] = __builtin_amdgcn_mfma_i32_32x32x32_i8(
                        a0[m], b0[n], acc[m][n], 0, 0, 0);
#pragma unroll
            for (int m = 0; m < 4; ++m)
#pragma unroll
                for (int n = 0; n < 4; ++n)
                    acc[m][n] = __builtin_amdgcn_mfma_i32_32x32x32_i8(
                        a1[m], b1[n], acc[m][n], 0, 0, 0);
        }

        asm volatile("s_waitcnt vmcnt(0)" ::: "memory");
        asm volatile("s_barrier" ::: "memory");
    }

    // ---- epilogue: C/D col = lane&31, row = (reg&3)+8*(reg>>2)+4*h ----
    const int col0 = bn * 256 + wc * 128 + l31;      // + n*32
    const int row00 = bm * 256 + wr * 128 + 4 * h;   // + m*32 + (reg&3)+8*(reg>>2)

#pragma unroll
    for (int m = 0; m < 4; ++m) {
        float sv[16];
#pragma unroll
        for (int rgi = 0; rgi < 16; ++rgi)
            sv[rgi] = sa[row00 + m * 32 + (rgi & 3) + 8 * (rgi >> 2)];
#pragma unroll
        for (int n = 0; n < 4; ++n) {
            const int col = col0 + n * 32;
            const float wn = wsc[col];
            const float bb = bias[col];
#pragma unroll
            for (int rgi = 0; rgi < 16; ++rgi) {
                const int row = row00 + m * 32 + (rgi & 3) + 8 * (rgi >> 2);
                out[(size_t)row * N + col] =
                    (float)acc[m][n][rgi] * sv[rgi] * wn + bb;
            }
        }
    }
}

// ---------------------------------------------------------------------------
extern "C" void kernel_launch(void* const* d_in, const int* in_sizes, int n_in,
                              void* d_out, int out_size, void* d_ws, size_t ws_size,
                              hipStream_t stream) {
    const float* inp  = (const float*)d_in[0];
    const int*   w32  = (const int*)d_in[1];   // int8 values carried as int32
    const float* wsc  = (const float*)d_in[2];
    const float* bias = (const float*)d_in[3];
    float* out = (float*)d_out;

    const int N = in_sizes[2];            // 4096
    const int K = in_sizes[1] / N;        // 4096
    const int M = in_sizes[0] / K;        // 8192

    // workspace: q[M*K] i8 | sa[M] f32 | W8[N*K] i8
    int8_t* q  = (int8_t*)d_ws;
    float*  sa = (float*)((char*)d_ws + (size_t)M * K);
    int8_t* w8 = (int8_t*)((char*)d_ws + (size_t)M * K + (size_t)M * 4 + 256);

    const size_t nw4 = ((size_t)N * K) / 4;
    pack_w<<<(int)(nw4 / 256), 256, 0, stream>>>(w32, (uint32_t*)w8);

    quant_rows<<<M, 256, 0, stream>>>(inp, q, sa, K);

    const int nwg = (M / 256) * (N / 256); // 512
    w8a8_gemm<<<nwg, 256, 0, stream>>>(q, w8, sa, wsc, bias, out, M, N, K);
}

// Round 8
// 206.905 us; speedup vs baseline: 1.1786x; 1.1786x over previous
//
#include <hip/hip_runtime.h>
#include <cstdint>

typedef __attribute__((ext_vector_type(4))) int int32x4;
typedef __attribute__((ext_vector_type(16))) int int32x16;

#define GLOBAL_AS __attribute__((address_space(1)))
#define LDS_AS    __attribute__((address_space(3)))

// ---------------------------------------------------------------------------
// Kernel 0: pack int32-carried weight [N*K] (values in [-128,127]) to int8.
// ---------------------------------------------------------------------------
__global__ __launch_bounds__(256) void pack_w(
    const int* __restrict__ w32, uint32_t* __restrict__ w8_as_u32)
{
    const size_t i = (size_t)blockIdx.x * 256 + threadIdx.x; // 4 elems each
    const int4 v = ((const int4*)w32)[i];
    w8_as_u32[i] = (v.x & 0xff) | ((v.y & 0xff) << 8) |
                   ((v.z & 0xff) << 16) | ((uint32_t)(v.w & 0xff) << 24);
}

// ---------------------------------------------------------------------------
// Kernel 1: per-row dynamic symmetric int8 quantization (K=4096).
// ---------------------------------------------------------------------------
__global__ __launch_bounds__(256) void quant_rows(
    const float* __restrict__ in, int8_t* __restrict__ q,
    float* __restrict__ sa, int K)
{
    const int row = blockIdx.x;
    const float4* rp = (const float4*)(in + (size_t)row * K);
    const int t = threadIdx.x;

    float amax = 0.f;
    float4 v[4];
#pragma unroll
    for (int i = 0; i < 4; ++i) {
        v[i] = rp[t + (i << 8)];
        amax = fmaxf(amax,
               fmaxf(fmaxf(fabsf(v[i].x), fabsf(v[i].y)),
                     fmaxf(fabsf(v[i].z), fabsf(v[i].w))));
    }

#pragma unroll
    for (int off = 32; off; off >>= 1)
        amax = fmaxf(amax, __shfl_xor(amax, off));
    __shared__ float smax[4];
    if ((t & 63) == 0) smax[t >> 6] = amax;
    __syncthreads();
    amax = fmaxf(fmaxf(smax[0], smax[1]), fmaxf(smax[2], smax[3]));

    const float scale = (amax > 0.f) ? (amax / 127.f) : 1.f;
    if (t == 0) sa[row] = scale;
    const float rs = 1.f / scale;

    int* qrow = (int*)(q + (size_t)row * K);
#pragma unroll
    for (int i = 0; i < 4; ++i) {
        int a = __float2int_rn(v[i].x * rs);
        int b = __float2int_rn(v[i].y * rs);
        int c = __float2int_rn(v[i].z * rs);
        int d = __float2int_rn(v[i].w * rs);
        a = max(-128, min(127, a));
        b = max(-128, min(127, b));
        c = max(-128, min(127, c));
        d = max(-128, min(127, d));
        qrow[t + (i << 8)] = (a & 0xff) | ((b & 0xff) << 8) |
                             ((c & 0xff) << 16) | ((d & 0xff) << 24);
    }
}

// ---------------------------------------------------------------------------
// Kernel 2 (R8): int8 GEMM, 256x256 tile, 8 waves x (128x64), 32x32x32 MFMA,
// fragment-major LDS (R7-proven 0-conflict), ring-4 + stage-2-ahead +
// counted vmcnt(4) (R6-proven schedule), 2 waves/SIMD (acc=128 VGPR),
// setprio around MFMA cluster (T5, pays at >=2 waves/SIMD).
//
// LDS per K-tile (32 KiB): A region 16 KiB: [mblk 0..7][kk 0..1][lane]
//   off = mblk*2048 + kk*1024 + lane*16;  B region same at +16384 (nblk).
// Every ds_read_b128 = base + lane*16 -> contiguous 1 KiB/wave -> 0 conflict
// (R7 measured; split-span reads cost 4 cyc/read, R4-R6 measured).
//
// Staging inverse map (LDS dest linear, rule #21): region slot j:
//   row = (j>>7)*32 + (j&31), col16 = (j>>5)&3.
// Thread t (0..511) covers A slots {t, t+512} and B slots {t, t+512}:
//   srow = ((t>>7)&3)*32 + (t&31) (+128 for the second), scol = ((t>>5)&3)<<4
//   -> 4 gload_lds per thread per K-tile.
//
// Ledger: prologue stages tiles 0,1 (8 loads); vmcnt(4) -> tile0 landed.
// Iter g: stage tile g+2 (4 loads) into ring (g+2)&3; compute tile g;
// end: vmcnt(4) [g>=NT-2: vmcnt(0)] -> tile g+1 landed, g+2 in flight;
// barrier. WAR: ring (g+2)&3 last read at iter g-2, 2 barriers back.
//
// Fragment maps (32x32 i8): A row = lane&31, k = (lane>>5)*16 + byte;
// B col = lane&31, same k. C/D: col = lane&31,
// row = (reg&3) + 8*(reg>>2) + 4*(lane>>5)  [guide-verified, dtype-indep].
// ---------------------------------------------------------------------------
__device__ __forceinline__ void async_load16(const int8_t* g, int8_t* lds) {
    __builtin_amdgcn_global_load_lds((const GLOBAL_AS char*)g,
                                     (LDS_AS char*)lds, 16, 0, 0);
}

__global__ __launch_bounds__(512, 2) void w8a8_gemm(
    const int8_t* __restrict__ Aq, const int8_t* __restrict__ W,
    const float* __restrict__ sa, const float* __restrict__ wsc,
    const float* __restrict__ bias, float* __restrict__ out,
    int M, int N, int K)
{
    __shared__ int8_t lds[4 * 32768]; // 128 KiB

    const int NB = N >> 8; // N/256
    const int nwg = gridDim.x;
    // XCD-aware swizzle (nwg % 8 == 0 -> bijective)
    const int cpx = nwg >> 3;
    const int wg = (blockIdx.x & 7) * cpx + (blockIdx.x >> 3);
    const int bm = wg / NB, bn = wg % NB;

    const int t = threadIdx.x;          // 0..511, 8 waves
    const int lane = t & 63, wid = t >> 6;
    const int wr = wid >> 2, wc = wid & 3;   // 2x4 wave grid: 128x64 each
    const int l31 = lane & 31, h = lane >> 5;

    // ---- staging: fragment-major inverse map, 4 loads/thread/tile ----
    const int srow = ((t >> 7) & 3) * 32 + (t & 31);   // 0..127
    const int scol = ((t >> 5) & 3) << 4;
    const int8_t* gA = Aq + ((size_t)bm * 256 + srow) * (size_t)K + scol;
    const int8_t* gB = W  + ((size_t)bn * 256 + srow) * (size_t)K + scol;
    const size_t hstep = (size_t)128 * K;  // +128 rows for slot t+512
    int8_t* ldsw = &lds[t * 16];

    auto stage_tile = [&](int slot, int kbyte) {
        const int8_t* sA = gA + kbyte;
        const int8_t* sB = gB + kbyte;
        int8_t* d = ldsw + slot * 32768;
        async_load16(sA, d);
        async_load16(sA + hstep, d + 8192);
        async_load16(sB, d + 16384);
        async_load16(sB + hstep, d + 16384 + 8192);
    };

    // ---- fragment read bases (contiguous: base + lane*16) ----
    const int aoff0 = wr * 8192 + lane * 16;           // + m*2048 + kk*1024
    const int boff0 = 16384 + wc * 4096 + lane * 16;   // + n*2048 + kk*1024

    int32x16 acc[4][2];
#pragma unroll
    for (int m = 0; m < 4; ++m)
#pragma unroll
        for (int n = 0; n < 2; ++n)
#pragma unroll
            for (int rgi = 0; rgi < 16; ++rgi)
                acc[m][n][rgi] = 0;

    const int NT = K >> 6; // 64 K-tiles

    // prologue: stage tiles 0 (ring 0) and 1 (ring 1)
    stage_tile(0, 0);
    stage_tile(1, 64);
    asm volatile("s_waitcnt vmcnt(4)" ::: "memory");
    asm volatile("s_barrier" ::: "memory");

    for (int g = 0; g < NT; ++g) {
        const int rbase = (g & 3) * 32768;
        const bool do_stage = (g + 2) < NT;

        int32x4 a0[4], b0[2], a1[4], b1[2];
#pragma unroll
        for (int m = 0; m < 4; ++m)
            a0[m] = *(const int32x4*)&lds[rbase + aoff0 + m * 2048];
#pragma unroll
        for (int n = 0; n < 2; ++n)
            b0[n] = *(const int32x4*)&lds[rbase + boff0 + n * 2048];

        if (do_stage) stage_tile((g + 2) & 3, (g + 2) << 6);

#pragma unroll
        for (int m = 0; m < 4; ++m)
            a1[m] = *(const int32x4*)&lds[rbase + aoff0 + m * 2048 + 1024];
#pragma unroll
        for (int n = 0; n < 2; ++n)
            b1[n] = *(const int32x4*)&lds[rbase + boff0 + n * 2048 + 1024];

        __builtin_amdgcn_s_setprio(1);
#pragma unroll
        for (int m = 0; m < 4; ++m)
#pragma unroll
            for (int n = 0; n < 2; ++n)
                acc[m][n] = __builtin_amdgcn_mfma_i32_32x32x32_i8(
                    a0[m], b0[n], acc[m][n], 0, 0, 0);
#pragma unroll
        for (int m = 0; m < 4; ++m)
#pragma unroll
            for (int n = 0; n < 2; ++n)
                acc[m][n] = __builtin_amdgcn_mfma_i32_32x32x32_i8(
                    a1[m], b1[n], acc[m][n], 0, 0, 0);
        __builtin_amdgcn_s_setprio(0);

        if (g < NT - 2)
            asm volatile("s_waitcnt vmcnt(4)" ::: "memory");
        else
            asm volatile("s_waitcnt vmcnt(0)" ::: "memory");
        asm volatile("s_barrier" ::: "memory");
    }

    // ---- epilogue: C/D col = lane&31, row = (reg&3)+8*(reg>>2)+4*h ----
    const int col0 = bn * 256 + wc * 64 + l31;       // + n*32
    const int row00 = bm * 256 + wr * 128 + 4 * h;   // + m*32 + (reg&3)+8*(reg>>2)

#pragma unroll
    for (int m = 0; m < 4; ++m) {
        float sv[16];
#pragma unroll
        for (int rgi = 0; rgi < 16; ++rgi)
            sv[rgi] = sa[row00 + m * 32 + (rgi & 3) + 8 * (rgi >> 2)];
#pragma unroll
        for (int n = 0; n < 2; ++n) {
            const int col = col0 + n * 32;
            const float wn = wsc[col];
            const float bb = bias[col];
#pragma unroll
            for (int rgi = 0; rgi < 16; ++rgi) {
                const int row = row00 + m * 32 + (rgi & 3) + 8 * (rgi >> 2);
                out[(size_t)row * N + col] =
                    (float)acc[m][n][rgi] * sv[rgi] * wn + bb;
            }
        }
    }
}

// ---------------------------------------------------------------------------
extern "C" void kernel_launch(void* const* d_in, const int* in_sizes, int n_in,
                              void* d_out, int out_size, void* d_ws, size_t ws_size,
                              hipStream_t stream) {
    const float* inp  = (const float*)d_in[0];
    const int*   w32  = (const int*)d_in[1];   // int8 values carried as int32
    const float* wsc  = (const float*)d_in[2];
    const float* bias = (const float*)d_in[3];
    float* out = (float*)d_out;

    const int N = in_sizes[2];            // 4096
    const int K = in_sizes[1] / N;        // 4096
    const int M = in_sizes[0] / K;        // 8192

    // workspace: q[M*K] i8 | sa[M] f32 | W8[N*K] i8
    int8_t* q  = (int8_t*)d_ws;
    float*  sa = (float*)((char*)d_ws + (size_t)M * K);
    int8_t* w8 = (int8_t*)((char*)d_ws + (size_t)M * K + (size_t)M * 4 + 256);

    const size_t nw4 = ((size_t)N * K) / 4;
    pack_w<<<(int)(nw4 / 256), 256, 0, stream>>>(w32, (uint32_t*)w8);

    quant_rows<<<M, 256, 0, stream>>>(inp, q, sa, K);

    const int nwg = (M / 256) * (N / 256); // 512
    w8a8_gemm<<<nwg, 512, 0, stream>>>(q, w8, sa, wsc, bias, out, M, N, K);
}